// Round 1
// baseline (7177.596 us; speedup 1.0000x reference)
//
#include <hip/hip_runtime.h>

// Problem constants (DiffeqSolver: S=1, b=64, N=50, F=64, H=128, K=2, T=40)
#define B_   64
#define N_   50
#define F_   64
#define H_   128
#define T_   40
#define E_   2450      // N*(N-1)
#define EPN  49        // edges per receiving node
#define NGRP 25        // node-groups per batch (2 nodes each)
#define EVAL_BLOCKS (B_ * NGRP)   // 1600

typedef __attribute__((ext_vector_type(8))) short  short8;   // 8 x bf16 (4 VGPRs)
typedef __attribute__((ext_vector_type(4))) float  float4_;  // MFMA accumulator

__device__ __forceinline__ unsigned short f2bf(float x) {
    union { float f; unsigned u; } v; v.f = x;
    unsigned r = v.u + 0x7fffu + ((v.u >> 16) & 1u);   // round-to-nearest-even
    return (unsigned short)(r >> 16);
}

// ---------------------------------------------------------------------------
// Setup 1: transpose weights to bf16, output-col-major: WT[k][j][i] = W[k][i][j]
// so a B-fragment (col j, k-run of 8) is one contiguous 16B load.
// ---------------------------------------------------------------------------
__global__ void k_weights(const float* __restrict__ W1, const float* __restrict__ W2,
                          unsigned short* __restrict__ w1t, unsigned short* __restrict__ w2t) {
    int tid = blockIdx.x * 256 + threadIdx.x;   // 0 .. 65535
    int mat = tid >> 15;
    int rr  = tid & 32767;
    int k = rr >> 14;
    int i = (rr >> 7) & 127;
    int j = rr & 127;
    const float* src = mat ? W2 : W1;
    unsigned short* dst = mat ? w2t : w1t;
    dst[(((k << 7) | j) << 7) | i] = f2bf(src[(((k << 7) | i) << 7) | j]);
}

// ---------------------------------------------------------------------------
// Setup 2: per (b, n): counting-sort the 49 senders by edge type.
// slots[0..g0-1] = type-0 senders, slots[a0 .. a0+g1-1] = type-1 senders
// (a0 = ceil16(g0)), everything else -1 (padding). Every 16-row MFMA tile
// then has a single uniform edge type: tile t is type (t*16 >= a0).
// ---------------------------------------------------------------------------
__global__ void k_sort(const int* __restrict__ graph, int* __restrict__ slots,
                       int* __restrict__ a0w) {
    int tid = blockIdx.x * 256 + threadIdx.x;
    if (tid >= B_ * N_) return;
    int b = tid / N_, n = tid % N_;
    const int* g = graph + b * E_ + n * EPN;
    int base = tid * 64;
    for (int j = 0; j < 64; j++) slots[base + j] = -1;
    int g0 = 0;
    for (int j = 0; j < EPN; j++) g0 += (g[j] == 0);
    int a0 = (g0 + 15) & ~15;
    a0w[tid] = a0;
    int p0 = 0, p1 = a0;
    for (int j = 0; j < EPN; j++) {
        int s = (j < n) ? j : j + 1;        // sender index (skip self-loop)
        if (g[j] == 0) slots[base + (p0++)] = s;
        else           slots[base + (p1++)] = s;
    }
}

// ---------------------------------------------------------------------------
// Setup 3: Y = first_point (f32 state), YB0 = bf16 mirror, out[:, t=0, :] = y0
// ---------------------------------------------------------------------------
__global__ void k_init(const float* __restrict__ fp, float* __restrict__ Y,
                       unsigned short* __restrict__ yb0, float* __restrict__ out) {
    int tid = blockIdx.x * 256 + threadIdx.x;   // 0 .. 204799
    float v = fp[tid];
    Y[tid] = v;
    yb0[tid] = f2bf(v);
    int bn = tid >> 6, f = tid & 63;
    out[bn * (T_ * F_) + f] = v;
}

// ---------------------------------------------------------------------------
// One ODE eval + RK4 stage update. Block = (batch b, nodes n0, n0+1).
// 128 edge-rows (2 nodes x 64 padded), col-split: wave w owns output cols
// [32w, 32w+32) so each W fragment is loaded once per block (L2-served).
// ---------------------------------------------------------------------------
__launch_bounds__(256, 3)
__global__ void k_eval(const unsigned short* __restrict__ ybIn,
                       unsigned short* __restrict__ ybOut,
                       float* __restrict__ Y, float* __restrict__ ACC,
                       const int* __restrict__ slotsW, const int* __restrict__ a0W,
                       const unsigned short* __restrict__ w1t,
                       const unsigned short* __restrict__ w2t,
                       const float* __restrict__ b1g, const float* __restrict__ b2g,
                       const float* __restrict__ W3, const float* __restrict__ b3,
                       const float* __restrict__ ts, float* __restrict__ out,
                       int t, int r) {
    __shared__ unsigned short yb[51][72];     // y[b] rows 0..49, row 50 = zeros; +pad
    __shared__ unsigned short hbuf[128][136]; // layer-1 output (GEMM2 A operand)
    __shared__ int   slt[2][64];
    __shared__ int   a0s[2];
    __shared__ float Lb1[2][128];
    __shared__ float Lb2[2][128];
    __shared__ float aggv[2][128];

    const int tid  = threadIdx.x;
    const int lane = tid & 63;
    const int w    = tid >> 6;
    const int blk  = blockIdx.x;
    const int b    = blk / NGRP;
    const int n0   = (blk % NGRP) * 2;

    // ---- stage y[b] (bf16), slots, a0, biases ----
    const unsigned short* ybb = ybIn + b * (N_ * F_);
    for (int idx = tid; idx < 400; idx += 256) {
        int row = idx >> 3, c8 = idx & 7;
        uint4 v = *(const uint4*)(ybb + row * 64 + c8 * 8);
        *(uint4*)(&yb[row][c8 * 8]) = v;
    }
    if (tid < 72) yb[50][tid] = 0;
    if (tid < 128) slt[tid >> 6][tid & 63] =
        slotsW[(b * N_ + n0 + (tid >> 6)) * 64 + (tid & 63)];
    if (tid < 2) a0s[tid] = a0W[b * N_ + n0 + tid];
    {   int k2 = tid >> 7, j2 = tid & 127;
        Lb1[k2][j2] = b1g[k2 * H_ + j2];
        Lb2[k2][j2] = b2g[k2 * H_ + j2]; }
    __syncthreads();

    const int lr = lane & 15;   // row-in-tile (A/C) / col-in-tile (B/C)
    const int q  = lane >> 4;
    const int colA = ((2 * w)     << 4) + lr;   // wave's first 16-col tile
    const int colB = ((2 * w + 1) << 4) + lr;   // wave's second 16-col tile

    int ktile[8];
    #pragma unroll
    for (int tt = 0; tt < 8; tt++)
        ktile[tt] = (((tt & 3) << 4) >= a0s[tt >> 2]) ? 1 : 0;

    const float4_ fz = {0.f, 0.f, 0.f, 0.f};

    // ================= GEMM1: h = relu(pre @ W1[k] + b1[k]) =================
    float4_ acc[8][2];
    #pragma unroll
    for (int tt = 0; tt < 8; tt++) { acc[tt][0] = fz; acc[tt][1] = fz; }

    #pragma unroll
    for (int kc = 0; kc < 4; kc++) {
        int kb = (kc << 5) + (q << 3);
        short8 B00 = *(const short8*)(w1t + ((      colA) << 7) + kb);  // kt=0
        short8 B01 = *(const short8*)(w1t + ((128 + colA) << 7) + kb);  // kt=1
        short8 B10 = *(const short8*)(w1t + ((      colB) << 7) + kb);
        short8 B11 = *(const short8*)(w1t + ((128 + colB) << 7) + kb);
        #pragma unroll
        for (int tt = 0; tt < 8; tt++) {
            int node = tt >> 2;
            int jn   = ((tt & 3) << 4) + lr;
            int slot = slt[node][jn];
            int inRecv = (kb >= 64);
            int row = inRecv ? (n0 + node) : (slot < 0 ? 50 : slot);
            int kk  = inRecv ? (kb - 64) : kb;
            short8 a = *(const short8*)(&yb[row][kk]);
            short8 Bx0 = ktile[tt] ? B01 : B00;
            short8 Bx1 = ktile[tt] ? B11 : B10;
            acc[tt][0] = __builtin_amdgcn_mfma_f32_16x16x32_bf16(a, Bx0, acc[tt][0], 0, 0, 0);
            acc[tt][1] = __builtin_amdgcn_mfma_f32_16x16x32_bf16(a, Bx1, acc[tt][1], 0, 0, 0);
        }
    }
    // epilogue: bias + relu -> hbuf (bf16)
    #pragma unroll
    for (int tt = 0; tt < 8; tt++) {
        int kt = ktile[tt];
        int r0 = q << 2;
        #pragma unroll
        for (int cw = 0; cw < 2; cw++) {
            int col = ((2 * w + cw) << 4) + lr;
            float bias = Lb1[kt][col];
            #pragma unroll
            for (int i = 0; i < 4; i++) {
                float hv = fmaxf(acc[tt][cw][i] + bias, 0.0f);
                hbuf[(tt << 4) + r0 + i][col] = f2bf(hv);
            }
        }
    }
    __syncthreads();

    // ================= GEMM2: m = relu(h @ W2[k] + b2[k]) ===================
    float4_ acc2[8][2];
    #pragma unroll
    for (int tt = 0; tt < 8; tt++) { acc2[tt][0] = fz; acc2[tt][1] = fz; }

    #pragma unroll
    for (int kc = 0; kc < 4; kc++) {
        int kb = (kc << 5) + (q << 3);
        short8 B00 = *(const short8*)(w2t + ((      colA) << 7) + kb);
        short8 B01 = *(const short8*)(w2t + ((128 + colA) << 7) + kb);
        short8 B10 = *(const short8*)(w2t + ((      colB) << 7) + kb);
        short8 B11 = *(const short8*)(w2t + ((128 + colB) << 7) + kb);
        #pragma unroll
        for (int tt = 0; tt < 8; tt++) {
            short8 a = *(const short8*)(&hbuf[(tt << 4) + lr][kb]);
            short8 Bx0 = ktile[tt] ? B01 : B00;
            short8 Bx1 = ktile[tt] ? B11 : B10;
            acc2[tt][0] = __builtin_amdgcn_mfma_f32_16x16x32_bf16(a, Bx0, acc2[tt][0], 0, 0, 0);
            acc2[tt][1] = __builtin_amdgcn_mfma_f32_16x16x32_bf16(a, Bx1, acc2[tt][1], 0, 0, 0);
        }
    }
    // epilogue: bias + relu, mask padding rows, reduce over edges -> aggv
    float aggp[2][2] = {{0.f, 0.f}, {0.f, 0.f}};
    #pragma unroll
    for (int tt = 0; tt < 8; tt++) {
        int node = tt >> 2, kt = ktile[tt], r0 = q << 2;
        #pragma unroll
        for (int cw = 0; cw < 2; cw++) {
            int col = ((2 * w + cw) << 4) + lr;
            float bias = Lb2[kt][col];
            float p = 0.f;
            #pragma unroll
            for (int i = 0; i < 4; i++) {
                int jn = ((tt & 3) << 4) + r0 + i;
                float mv = fmaxf(acc2[tt][cw][i] + bias, 0.f);
                p += (slt[node][jn] >= 0) ? mv : 0.f;
            }
            p += __shfl_down(p, 32);
            p += __shfl_down(p, 16);
            aggp[node][cw] += p;   // valid on lanes 0..15
        }
    }
    if (lane < 16) {
        #pragma unroll
        for (int node = 0; node < 2; node++)
            #pragma unroll
            for (int cw = 0; cw < 2; cw++)
                aggv[node][((2 * w + cw) << 4) + lane] = aggp[node][cw];
    }
    __syncthreads();

    // ============ dy = tanh(agg*inv_n @ W3 + b3); RK4 stage update ==========
    if (tid < 128) {
        int node = tid >> 6, f = tid & 63;
        int n = n0 + node;
        float s = 0.f;
        #pragma unroll 4
        for (int h = 0; h < H_; h++) s += aggv[node][h] * W3[h * F_ + f];
        const float inv_n = 1.0f / (float)N_;
        float dy = tanhf(s * inv_n + b3[f]);
        float dt = ts[t + 1] - ts[t];
        int idx = (b * N_ + n) * F_ + f;
        float ybase = Y[idx];
        float ysv;
        if (r == 0)      { ACC[idx] = dy;          ysv = ybase + 0.5f * dt * dy; }
        else if (r == 1) { ACC[idx] += 2.f * dy;   ysv = ybase + 0.5f * dt * dy; }
        else if (r == 2) { ACC[idx] += 2.f * dy;   ysv = ybase + dt * dy; }
        else {
            float af = ACC[idx] + dy;
            float yn = ybase + dt * (1.0f / 6.0f) * af;
            Y[idx] = yn;
            out[(b * N_ + n) * (T_ * F_) + (t + 1) * F_ + f] = yn;
            ysv = yn;
        }
        ybOut[idx] = f2bf(ysv);
    }
}

// ---------------------------------------------------------------------------
extern "C" void kernel_launch(void* const* d_in, const int* in_sizes, int n_in,
                              void* d_out, int out_size, void* d_ws, size_t ws_size,
                              hipStream_t stream) {
    const float* fp    = (const float*)d_in[0];   // first_point [1,3200,64]
    const float* ts    = (const float*)d_in[1];   // time_steps [40]
    const int*   graph = (const int*)  d_in[2];   // [64,2450]
    const float* W1    = (const float*)d_in[3];   // [2,128,128]
    const float* b1    = (const float*)d_in[4];   // [2,128]
    const float* W2    = (const float*)d_in[5];   // [2,128,128]
    const float* b2    = (const float*)d_in[6];   // [2,128]
    const float* W3    = (const float*)d_in[7];   // [128,64]
    const float* b3    = (const float*)d_in[8];   // [64]
    float* out = (float*)d_out;

    char* ws = (char*)d_ws;
    size_t off = 0;
    auto alloc = [&](size_t bytes) {
        void* p = ws + off;
        off = (off + bytes + 255) & ~(size_t)255;
        return p;
    };
    float*          Y    = (float*)alloc(204800 * 4);
    float*          ACC  = (float*)alloc(204800 * 4);
    unsigned short* yb0  = (unsigned short*)alloc(204800 * 2);
    unsigned short* yb1  = (unsigned short*)alloc(204800 * 2);
    unsigned short* w1t  = (unsigned short*)alloc(32768 * 2);
    unsigned short* w2t  = (unsigned short*)alloc(32768 * 2);
    int*            slots = (int*)alloc(3200 * 64 * 4);
    int*            a0w   = (int*)alloc(3200 * 4);

    k_weights<<<256, 256, 0, stream>>>(W1, W2, w1t, w2t);
    k_sort<<<13, 256, 0, stream>>>(graph, slots, a0w);
    k_init<<<800, 256, 0, stream>>>(fp, Y, yb0, out);

    unsigned short* bin  = yb0;
    unsigned short* bout = yb1;
    for (int s = 0; s < T_ - 1; s++) {
        for (int r = 0; r < 4; r++) {
            k_eval<<<EVAL_BLOCKS, 256, 0, stream>>>(bin, bout, Y, ACC, slots, a0w,
                                                    w1t, w2t, b1, b2, W3, b3,
                                                    ts, out, s, r);
            unsigned short* tmp = bin; bin = bout; bout = tmp;
        }
    }
}

// Round 2
// 6487.125 us; speedup vs baseline: 1.1064x; 1.1064x over previous
//
#include <hip/hip_runtime.h>

// Problem constants (DiffeqSolver: S=1, b=64, N=50, F=64, H=128, K=2, T=40)
#define B_   64
#define N_   50
#define F_   64
#define H_   128
#define T_   40
#define E_   2450      // N*(N-1)
#define EPN  49        // edges per receiving node
#define NGRP 25        // node-groups per batch (2 nodes each)
#define EVAL_BLOCKS (B_ * NGRP)   // 1600

typedef __attribute__((ext_vector_type(8))) short  short8;   // 8 x bf16 (4 VGPRs)
typedef __attribute__((ext_vector_type(4))) float  float4_;  // MFMA accumulator

__device__ __forceinline__ unsigned short f2bf(float x) {
    union { float f; unsigned u; } v; v.f = x;
    unsigned r = v.u + 0x7fffu + ((v.u >> 16) & 1u);   // round-to-nearest-even
    return (unsigned short)(r >> 16);
}
__device__ __forceinline__ float bf2f(unsigned short x) {
    union { unsigned u; float f; } v; v.u = ((unsigned)x) << 16;
    return v.f;
}

// ---------------------------------------------------------------------------
// Setup 1: transpose weights to bf16, output-col-major: WT[k][j][i] = W[k][i][j]
// ---------------------------------------------------------------------------
__global__ void k_weights(const float* __restrict__ W1, const float* __restrict__ W2,
                          unsigned short* __restrict__ w1t, unsigned short* __restrict__ w2t) {
    int tid = blockIdx.x * 256 + threadIdx.x;   // 0 .. 65535
    int mat = tid >> 15;
    int rr  = tid & 32767;
    int k = rr >> 14;
    int i = (rr >> 7) & 127;
    int j = rr & 127;
    const float* src = mat ? W2 : W1;
    unsigned short* dst = mat ? w2t : w1t;
    dst[(((k << 7) | j) << 7) | i] = f2bf(src[(((k << 7) | i) << 7) | j]);
}

// Setup 1b: w3t[f][h] = bf16(W3[h][f])  (f-major for contiguous per-thread reads)
__global__ void k_w3(const float* __restrict__ W3, unsigned short* __restrict__ w3t) {
    int tid = blockIdx.x * 256 + threadIdx.x;   // 0 .. 8191
    int f = tid >> 7, h = tid & 127;
    w3t[(f << 7) | h] = f2bf(W3[(h << 6) | f]);
}

// ---------------------------------------------------------------------------
// Setup 2: per (b, n): counting-sort the 49 senders by edge type.
// slots[0..g0-1]=type-0 senders, slots[a0..a0+g1-1]=type-1 (a0=ceil16(g0)),
// rest -1.  a0w packs a0 | g0<<8 | g1<<16 for arithmetic pad-masking.
// ---------------------------------------------------------------------------
__global__ void k_sort(const int* __restrict__ graph, int* __restrict__ slots,
                       int* __restrict__ a0w) {
    int tid = blockIdx.x * 256 + threadIdx.x;
    if (tid >= B_ * N_) return;
    int b = tid / N_, n = tid % N_;
    const int* g = graph + b * E_ + n * EPN;
    int base = tid * 64;
    for (int j = 0; j < 64; j++) slots[base + j] = -1;
    int g0 = 0;
    for (int j = 0; j < EPN; j++) g0 += (g[j] == 0);
    int a0 = (g0 + 15) & ~15;
    int g1 = EPN - g0;
    a0w[tid] = a0 | (g0 << 8) | (g1 << 16);
    int p0 = 0, p1 = a0;
    for (int j = 0; j < EPN; j++) {
        int s = (j < n) ? j : j + 1;        // sender index (skip self-loop)
        if (g[j] == 0) slots[base + (p0++)] = s;
        else           slots[base + (p1++)] = s;
    }
}

// ---------------------------------------------------------------------------
// Setup 3: Y = first_point (f32 state), YB0 = bf16 mirror, out[:, t=0, :] = y0
// ---------------------------------------------------------------------------
__global__ void k_init(const float* __restrict__ fp, float* __restrict__ Y,
                       unsigned short* __restrict__ yb0, float* __restrict__ out) {
    int tid = blockIdx.x * 256 + threadIdx.x;   // 0 .. 204799
    float v = fp[tid];
    Y[tid] = v;
    yb0[tid] = f2bf(v);
    int bn = tid >> 6, f = tid & 63;
    out[bn * (T_ * F_) + f] = v;
}

// ---------------------------------------------------------------------------
// One ODE eval + RK4 stage update. Block = (batch b, nodes n0, n0+1).
// ---------------------------------------------------------------------------
__launch_bounds__(256, 3)
__global__ void k_eval(const unsigned short* __restrict__ ybIn,
                       unsigned short* __restrict__ ybOut,
                       float* __restrict__ Y, float* __restrict__ ACC,
                       const int* __restrict__ slotsW, const int* __restrict__ a0W,
                       const unsigned short* __restrict__ w1t,
                       const unsigned short* __restrict__ w2t,
                       const float* __restrict__ b1g, const float* __restrict__ b2g,
                       const unsigned short* __restrict__ w3t, const float* __restrict__ b3,
                       const float* __restrict__ ts, float* __restrict__ out,
                       int t, int r) {
    __shared__ unsigned short yb[51][72];     // y[b] rows 0..49, row 50 = zeros
    __shared__ unsigned short hbuf[128][136]; // layer-1 output (GEMM2 A operand)
    __shared__ int   slt[2][64];
    __shared__ float aggv[2][128];

    const int tid  = threadIdx.x;
    const int lane = tid & 63;
    const int w    = tid >> 6;
    const int blk  = blockIdx.x;
    const int b    = blk / NGRP;
    const int n0   = (blk % NGRP) * 2;

    // ---- stage y[b] (bf16) + slots ----
    const unsigned short* ybb = ybIn + b * (N_ * F_);
    for (int idx = tid; idx < 400; idx += 256) {
        int row = idx >> 3, c8 = idx & 7;
        uint4 v = *(const uint4*)(ybb + row * 64 + c8 * 8);
        *(uint4*)(&yb[row][c8 * 8]) = v;
    }
    if (tid < 72) yb[50][tid] = 0;
    if (tid < 128) slt[tid >> 6][tid & 63] =
        slotsW[(b * N_ + n0 + (tid >> 6)) * 64 + (tid & 63)];

    // uniform per-block metadata (scalar loads)
    int pk0 = a0W[b * N_ + n0], pk1 = a0W[b * N_ + n0 + 1];
    int a0s[2] = { pk0 & 0xff, pk1 & 0xff };
    int limT[2][2];  // [node][ktype] -> valid-count limit for that region
    limT[0][0] = (pk0 >> 8) & 0xff;  limT[0][1] = a0s[0] + ((pk0 >> 16) & 0xff);
    limT[1][0] = (pk1 >> 8) & 0xff;  limT[1][1] = a0s[1] + ((pk1 >> 16) & 0xff);

    const int lr = lane & 15;
    const int q  = lane >> 4;
    const int colA = ((2 * w)     << 4) + lr;
    const int colB = ((2 * w + 1) << 4) + lr;

    // hoisted biases (L2-hot)
    float b1A0 = b1g[colA], b1A1 = b1g[128 + colA];
    float b1B0 = b1g[colB], b1B1 = b1g[128 + colB];
    float b2A0 = b2g[colA], b2A1 = b2g[128 + colA];
    float b2B0 = b2g[colB], b2B1 = b2g[128 + colB];

    int ktile[8], lim[8];
    #pragma unroll
    for (int tt = 0; tt < 8; tt++) {
        int node = tt >> 2;
        ktile[tt] = (((tt & 3) << 4) >= a0s[node]) ? 1 : 0;
        lim[tt]   = limT[node][ktile[tt]];
    }

    __syncthreads();

    // sender rows for this lane's A-fragments (read slots ONCE)
    int rowS[8];
    #pragma unroll
    for (int tt = 0; tt < 8; tt++) {
        int sv = slt[tt >> 2][((tt & 3) << 4) + lr];
        rowS[tt] = (sv < 0) ? 50 : sv;
    }

    const float4_ fz = {0.f, 0.f, 0.f, 0.f};

    // ================= GEMM1: h = relu(pre @ W1[k] + b1[k]) =================
    float4_ acc[8][2];
    #pragma unroll
    for (int tt = 0; tt < 8; tt++) { acc[tt][0] = fz; acc[tt][1] = fz; }

    // --- sender K-half (k = 0..63 of W1) ---
    #pragma unroll
    for (int kc = 0; kc < 2; kc++) {
        int kb = (kc << 5) + (q << 3);
        short8 B00 = *(const short8*)(w1t + ((      colA) << 7) + kb);
        short8 B01 = *(const short8*)(w1t + ((128 + colA) << 7) + kb);
        short8 B10 = *(const short8*)(w1t + ((      colB) << 7) + kb);
        short8 B11 = *(const short8*)(w1t + ((128 + colB) << 7) + kb);
        #pragma unroll
        for (int tt = 0; tt < 8; tt++) {
            short8 a = *(const short8*)(&yb[rowS[tt]][kb]);
            short8 Bx0 = ktile[tt] ? B01 : B00;
            short8 Bx1 = ktile[tt] ? B11 : B10;
            acc[tt][0] = __builtin_amdgcn_mfma_f32_16x16x32_bf16(a, Bx0, acc[tt][0], 0, 0, 0);
            acc[tt][1] = __builtin_amdgcn_mfma_f32_16x16x32_bf16(a, Bx1, acc[tt][1], 0, 0, 0);
        }
    }
    // --- receiver K-half (k = 64..127): A-row is the SAME for all tiles of a node ---
    #pragma unroll
    for (int kc = 0; kc < 2; kc++) {
        int kb  = (kc << 5) + (q << 3);      // offset within y row
        int kbW = 64 + kb;                   // W1 k-index
        short8 B00 = *(const short8*)(w1t + ((      colA) << 7) + kbW);
        short8 B01 = *(const short8*)(w1t + ((128 + colA) << 7) + kbW);
        short8 B10 = *(const short8*)(w1t + ((      colB) << 7) + kbW);
        short8 B11 = *(const short8*)(w1t + ((128 + colB) << 7) + kbW);
        short8 aR0 = *(const short8*)(&yb[n0    ][kb]);
        short8 aR1 = *(const short8*)(&yb[n0 + 1][kb]);
        #pragma unroll
        for (int tt = 0; tt < 8; tt++) {
            short8 a = (tt < 4) ? aR0 : aR1;   // compile-time select (unrolled)
            short8 Bx0 = ktile[tt] ? B01 : B00;
            short8 Bx1 = ktile[tt] ? B11 : B10;
            acc[tt][0] = __builtin_amdgcn_mfma_f32_16x16x32_bf16(a, Bx0, acc[tt][0], 0, 0, 0);
            acc[tt][1] = __builtin_amdgcn_mfma_f32_16x16x32_bf16(a, Bx1, acc[tt][1], 0, 0, 0);
        }
    }

    // epilogue 1: bias + relu -> hbuf (bf16)
    #pragma unroll
    for (int tt = 0; tt < 8; tt++) {
        int r0 = q << 2;
        #pragma unroll
        for (int cw = 0; cw < 2; cw++) {
            int col = ((2 * w + cw) << 4) + lr;
            float bias = ktile[tt] ? (cw ? b1B1 : b1A1) : (cw ? b1B0 : b1A0);
            #pragma unroll
            for (int i = 0; i < 4; i++) {
                float hv = fmaxf(acc[tt][cw][i] + bias, 0.0f);
                hbuf[(tt << 4) + r0 + i][col] = f2bf(hv);
            }
        }
    }
    __syncthreads();

    // ================= GEMM2: m = relu(h @ W2[k] + b2[k]) ===================
    float4_ acc2[8][2];
    #pragma unroll
    for (int tt = 0; tt < 8; tt++) { acc2[tt][0] = fz; acc2[tt][1] = fz; }

    #pragma unroll
    for (int kc = 0; kc < 4; kc++) {
        int kb = (kc << 5) + (q << 3);
        short8 B00 = *(const short8*)(w2t + ((      colA) << 7) + kb);
        short8 B01 = *(const short8*)(w2t + ((128 + colA) << 7) + kb);
        short8 B10 = *(const short8*)(w2t + ((      colB) << 7) + kb);
        short8 B11 = *(const short8*)(w2t + ((128 + colB) << 7) + kb);
        #pragma unroll
        for (int tt = 0; tt < 8; tt++) {
            short8 a = *(const short8*)(&hbuf[(tt << 4) + lr][kb]);
            short8 Bx0 = ktile[tt] ? B01 : B00;
            short8 Bx1 = ktile[tt] ? B11 : B10;
            acc2[tt][0] = __builtin_amdgcn_mfma_f32_16x16x32_bf16(a, Bx0, acc2[tt][0], 0, 0, 0);
            acc2[tt][1] = __builtin_amdgcn_mfma_f32_16x16x32_bf16(a, Bx1, acc2[tt][1], 0, 0, 0);
        }
    }

    // epilogue 2: bias + relu, arithmetic pad-mask, reduce over edges -> aggv
    float aggp[2][2] = {{0.f, 0.f}, {0.f, 0.f}};
    #pragma unroll
    for (int tt = 0; tt < 8; tt++) {
        int node = tt >> 2, r0 = q << 2;
        #pragma unroll
        for (int cw = 0; cw < 2; cw++) {
            float bias = ktile[tt] ? (cw ? b2B1 : b2A1) : (cw ? b2B0 : b2A0);
            float p = 0.f;
            #pragma unroll
            for (int i = 0; i < 4; i++) {
                int jn = ((tt & 3) << 4) + r0 + i;
                float mv = fmaxf(acc2[tt][cw][i] + bias, 0.f);
                p += (jn < lim[tt]) ? mv : 0.f;
            }
            p += __shfl_down(p, 32);
            p += __shfl_down(p, 16);
            aggp[node][cw] += p;   // valid on lanes 0..15
        }
    }
    if (lane < 16) {
        #pragma unroll
        for (int node = 0; node < 2; node++)
            #pragma unroll
            for (int cw = 0; cw < 2; cw++)
                aggv[node][((2 * w + cw) << 4) + lane] = aggp[node][cw];
    }
    __syncthreads();

    // ============ dy = tanh(agg*inv_n @ W3 + b3); RK4 stage update ==========
    if (tid < 128) {
        int node = tid >> 6, f = tid & 63;
        int n = n0 + node;
        const float4_* av = (const float4_*)(&aggv[node][0]);
        float s = 0.f;
        #pragma unroll
        for (int c = 0; c < 16; c++) {
            short8 wv = *(const short8*)(w3t + (f << 7) + (c << 3));
            float4_ a0v = av[2 * c], a1v = av[2 * c + 1];
            s += a0v[0] * bf2f((unsigned short)wv[0]);
            s += a0v[1] * bf2f((unsigned short)wv[1]);
            s += a0v[2] * bf2f((unsigned short)wv[2]);
            s += a0v[3] * bf2f((unsigned short)wv[3]);
            s += a1v[0] * bf2f((unsigned short)wv[4]);
            s += a1v[1] * bf2f((unsigned short)wv[5]);
            s += a1v[2] * bf2f((unsigned short)wv[6]);
            s += a1v[3] * bf2f((unsigned short)wv[7]);
        }
        const float inv_n = 1.0f / (float)N_;
        float x = s * inv_n + b3[f];
        // tanh(x) = 1 - 2/(exp(2x)+1): branch-free, saturates correctly
        float e = __expf(2.0f * x);
        float dy = 1.0f - 2.0f / (e + 1.0f);
        float dt = ts[t + 1] - ts[t];
        int idx = (b * N_ + n) * F_ + f;
        float ybase = Y[idx];
        float ysv;
        if (r == 0)      { ACC[idx] = dy;          ysv = ybase + 0.5f * dt * dy; }
        else if (r == 1) { ACC[idx] += 2.f * dy;   ysv = ybase + 0.5f * dt * dy; }
        else if (r == 2) { ACC[idx] += 2.f * dy;   ysv = ybase + dt * dy; }
        else {
            float af = ACC[idx] + dy;
            float yn = ybase + dt * (1.0f / 6.0f) * af;
            Y[idx] = yn;
            out[(b * N_ + n) * (T_ * F_) + (t + 1) * F_ + f] = yn;
            ysv = yn;
        }
        ybOut[idx] = f2bf(ysv);
    }
}

// ---------------------------------------------------------------------------
extern "C" void kernel_launch(void* const* d_in, const int* in_sizes, int n_in,
                              void* d_out, int out_size, void* d_ws, size_t ws_size,
                              hipStream_t stream) {
    const float* fp    = (const float*)d_in[0];   // first_point [1,3200,64]
    const float* ts    = (const float*)d_in[1];   // time_steps [40]
    const int*   graph = (const int*)  d_in[2];   // [64,2450]
    const float* W1    = (const float*)d_in[3];   // [2,128,128]
    const float* b1    = (const float*)d_in[4];   // [2,128]
    const float* W2    = (const float*)d_in[5];   // [2,128,128]
    const float* b2    = (const float*)d_in[6];   // [2,128]
    const float* W3    = (const float*)d_in[7];   // [128,64]
    const float* b3    = (const float*)d_in[8];   // [64]
    float* out = (float*)d_out;

    char* ws = (char*)d_ws;
    size_t off = 0;
    auto alloc = [&](size_t bytes) {
        void* p = ws + off;
        off = (off + bytes + 255) & ~(size_t)255;
        return p;
    };
    float*          Y    = (float*)alloc(204800 * 4);
    float*          ACC  = (float*)alloc(204800 * 4);
    unsigned short* yb0  = (unsigned short*)alloc(204800 * 2);
    unsigned short* yb1  = (unsigned short*)alloc(204800 * 2);
    unsigned short* w1t  = (unsigned short*)alloc(32768 * 2);
    unsigned short* w2t  = (unsigned short*)alloc(32768 * 2);
    unsigned short* w3t  = (unsigned short*)alloc(8192 * 2);
    int*            slots = (int*)alloc(3200 * 64 * 4);
    int*            a0w   = (int*)alloc(3200 * 4);

    k_weights<<<256, 256, 0, stream>>>(W1, W2, w1t, w2t);
    k_w3<<<32, 256, 0, stream>>>(W3, w3t);
    k_sort<<<13, 256, 0, stream>>>(graph, slots, a0w);
    k_init<<<800, 256, 0, stream>>>(fp, Y, yb0, out);

    unsigned short* bin  = yb0;
    unsigned short* bout = yb1;
    for (int s = 0; s < T_ - 1; s++) {
        for (int r = 0; r < 4; r++) {
            k_eval<<<EVAL_BLOCKS, 256, 0, stream>>>(bin, bout, Y, ACC, slots, a0w,
                                                    w1t, w2t, b1, b2, w3t, b3,
                                                    ts, out, s, r);
            unsigned short* tmp = bin; bin = bout; bout = tmp;
        }
    }
}